// Round 1
// baseline (272.453 us; speedup 1.0000x reference)
//
#include <hip/hip_runtime.h>
#include <math.h>

#define T_TOK   500000
#define NF4     8000000      // float4 count of token_embs (500000*64/4)
#define NTILES  7813         // ceil(500000/64)
#define GRID_A  1024
#define GRID_C  2048

// ws layout (bytes)
#define OFF_PARTA 0u                          // double[GRID_A][128]  (1 MB)
#define OFF_COLF  (1u<<20)                    // double[128]
#define OFF_CNT   ((1u<<20) + 4096u)          // int
#define OFF_PSUM  (2u<<20)                    // float[GRID_C][512]   (4 MB)
#define OFF_PMASS ((2u<<20) + GRID_C*512u*4u) // float[GRID_C][8]

// ---------------- Pass A: per-column sum / sumsq (double) ----------------
__global__ __launch_bounds__(256) void k_colstats(const float4* __restrict__ x4,
                                                  double* __restrict__ parta) {
  const int tid  = threadIdx.x;
  const int gtid = blockIdx.x * 256 + tid;
  double s0=0,s1=0,s2=0,s3=0,q0=0,q1=0,q2=0,q3=0;
  for (int f = gtid; f < NF4; f += GRID_A * 256) {
    float4 v = x4[f];
    double a=v.x, b=v.y, c=v.z, d=v.w;
    s0+=a; s1+=b; s2+=c; s3+=d;
    q0+=a*a; q1+=b*b; q2+=c*c; q3+=d*d;
  }
  __shared__ double red[256][4];
  red[tid][0]=s0; red[tid][1]=s1; red[tid][2]=s2; red[tid][3]=s3;
  __syncthreads();
  if (tid < 64) {
    int g = tid >> 2, i = tid & 3;
    double t = 0;
    #pragma unroll
    for (int j = 0; j < 16; j++) t += red[g + 16*j][i];
    parta[(size_t)blockIdx.x * 128 + tid] = t;
  }
  __syncthreads();
  red[tid][0]=q0; red[tid][1]=q1; red[tid][2]=q2; red[tid][3]=q3;
  __syncthreads();
  if (tid < 64) {
    int g = tid >> 2, i = tid & 3;
    double t = 0;
    #pragma unroll
    for (int j = 0; j < 16; j++) t += red[g + 16*j][i];
    parta[(size_t)blockIdx.x * 128 + 64 + tid] = t;
  }
}

// ---------------- Pass B1: reduce block partials per column-stat ----------------
__global__ __launch_bounds__(256) void k_colreduce(const double* __restrict__ parta,
                                                   double* __restrict__ colf) {
  const int c = blockIdx.x;  // 0..127
  double t = 0;
  for (int b = threadIdx.x; b < GRID_A; b += 256) t += parta[(size_t)b * 128 + c];
  __shared__ double r[256];
  r[threadIdx.x] = t;
  __syncthreads();
  for (int s = 128; s > 0; s >>= 1) {
    if (threadIdx.x < s) r[threadIdx.x] += r[threadIdx.x + s];
    __syncthreads();
  }
  if (threadIdx.x == 0) colf[c] = r[0];
}

// ---------------- Pass B2: variance -> cluster_count ----------------
__global__ __launch_bounds__(64) void k_count(const double* __restrict__ colf,
                                              int* __restrict__ cnt) {
  const int c = threadIdx.x;  // 0..63
  double sum = colf[c], sq = colf[64 + c];
  double var = (sq - sum * sum / (double)T_TOK) / (double)(T_TOK - 1);
  for (int off = 32; off; off >>= 1) var += __shfl_xor(var, off);
  if (c == 0) {
    double vm = var / 64.0;
    int k = (int)floor(vm * 5.0 + 2.0);
    if (k < 2) k = 2;
    if (k > 8) k = 8;
    *cnt = k;
  }
}

// ---------------- Pass C: distances + gumbel softmax + weighted accumulation ----------------
__global__ __launch_bounds__(64) void k_main(const float4* __restrict__ x4,
                                             const float4* __restrict__ gu4,
                                             const float* __restrict__ cm,
                                             const int* __restrict__ cntp,
                                             float* __restrict__ psum,
                                             float* __restrict__ pmass) {
  const int lane = threadIdx.x;
  __shared__ float X[64 * 65];  // stride 65 (odd) -> conflict-free row & column access

  // ||c_k||^2 (uniform indices -> scalar loads, hoisted once)
  float c2[8];
  #pragma unroll
  for (int k = 0; k < 8; k++) {
    float s = 0.f;
    for (int d = 0; d < 64; d++) { float cv = cm[k*64 + d]; s += cv * cv; }
    c2[k] = s;
  }
  const int cnt = *cntp;

  float acc[8] = {0,0,0,0,0,0,0,0};  // acc[k] for d = lane
  float msr[8] = {0,0,0,0,0,0,0,0};  // per-lane mass partials

  for (int tile = blockIdx.x; tile < NTILES; tile += GRID_C) {
    const int t0 = tile * 64;
    __syncthreads();
    // stage 64x64 f32 tile (coalesced), zero-fill OOB (tail tile)
    #pragma unroll
    for (int j = 0; j < 16; j++) {
      int q = j * 64 + lane;
      long fi = (long)t0 * 16 + q;
      float4 v = make_float4(0.f, 0.f, 0.f, 0.f);
      if (fi < NF4) v = x4[fi];
      float* p = &X[(q >> 4) * 65 + (q & 15) * 4];
      p[0]=v.x; p[1]=v.y; p[2]=v.z; p[3]=v.w;
    }
    __syncthreads();

    const int tok = t0 + lane;
    const bool valid = tok < T_TOK;

    // dots with 8 centers (x from LDS row, centers via uniform/scalar loads)
    float dot[8] = {0,0,0,0,0,0,0,0};
    #pragma unroll
    for (int c = 0; c < 16; c++) {
      float xv0 = X[lane*65 + c*4 + 0];
      float xv1 = X[lane*65 + c*4 + 1];
      float xv2 = X[lane*65 + c*4 + 2];
      float xv3 = X[lane*65 + c*4 + 3];
      #pragma unroll
      for (int k = 0; k < 8; k++) {
        dot[k] += xv0 * cm[k*64 + c*4 + 0] + xv1 * cm[k*64 + c*4 + 1]
                + xv2 * cm[k*64 + c*4 + 2] + xv3 * cm[k*64 + c*4 + 3];
      }
    }

    // gumbel + masked softmax, fully per-lane (x^2 term cancels in softmax)
    float a[8];
    if (valid) {
      float4 g0 = gu4[(size_t)tok * 2 + 0];
      float4 g1 = gu4[(size_t)tok * 2 + 1];
      float g[8] = {g0.x, g0.y, g0.z, g0.w, g1.x, g1.y, g1.z, g1.w};
      float lg[8];
      float m = -1e38f;
      #pragma unroll
      for (int k = 0; k < 8; k++) {
        float noise = -__logf(-__logf(g[k]));
        lg[k] = 2.f * dot[k] - c2[k] + noise;
        if (k < cnt && lg[k] > m) m = lg[k];
      }
      float ssum = 0.f;
      #pragma unroll
      for (int k = 0; k < 8; k++) {
        float e = (k < cnt) ? __expf(lg[k] - m) : 0.f;
        a[k] = e; ssum += e;
      }
      float inv = 1.f / ssum;
      #pragma unroll
      for (int k = 0; k < 8; k++) a[k] *= inv;
    } else {
      #pragma unroll
      for (int k = 0; k < 8; k++) a[k] = 0.f;
    }

    #pragma unroll
    for (int k = 0; k < 8; k++) msr[k] += a[k];

    // acc[k][lane] += sum_t a_t[k] * X[t][lane]  (readlane broadcast, VALU pipe)
    #pragma unroll 8
    for (int t = 0; t < 64; t++) {
      float xv = X[t * 65 + lane];
      #pragma unroll
      for (int k = 0; k < 8; k++) {
        float ak = __int_as_float(__builtin_amdgcn_readlane(__float_as_int(a[k]), t));
        acc[k] += ak * xv;
      }
    }
  }

  // per-block partials (deterministic, no atomics)
  #pragma unroll
  for (int k = 0; k < 8; k++)
    psum[(size_t)blockIdx.x * 512 + k * 64 + lane] = acc[k];
  #pragma unroll
  for (int k = 0; k < 8; k++) {
    float v = msr[k];
    for (int off = 32; off; off >>= 1) v += __shfl_xor(v, off);
    if (lane == 0) pmass[(size_t)blockIdx.x * 8 + k] = v;
  }
}

// ---------------- Pass D: reduce partials + normalize ----------------
__global__ __launch_bounds__(256) void k_final(const float* __restrict__ psum,
                                               const float* __restrict__ pmass,
                                               const int* __restrict__ cntp,
                                               float* __restrict__ out) {
  const int kd = blockIdx.x;  // 0..511
  const int k = kd >> 6;
  float s = 0.f, m = 0.f;
  for (int b = threadIdx.x; b < GRID_C; b += 256) {
    s += psum[(size_t)b * 512 + kd];
    m += pmass[(size_t)b * 8 + k];
  }
  __shared__ float rs[256], rm[256];
  rs[threadIdx.x] = s; rm[threadIdx.x] = m;
  __syncthreads();
  for (int t = 128; t > 0; t >>= 1) {
    if (threadIdx.x < t) { rs[threadIdx.x] += rs[threadIdx.x + t]; rm[threadIdx.x] += rm[threadIdx.x + t]; }
    __syncthreads();
  }
  if (threadIdx.x == 0) {
    int cnt = *cntp;
    out[kd] = (k < cnt) ? (rs[0] / (rm[0] + 1e-8f)) : 0.f;
  }
}

extern "C" void kernel_launch(void* const* d_in, const int* in_sizes, int n_in,
                              void* d_out, int out_size, void* d_ws, size_t ws_size,
                              hipStream_t stream) {
  const float* embs = (const float*)d_in[0];
  const float* gum  = (const float*)d_in[1];
  const float* cent = (const float*)d_in[2];
  char* ws = (char*)d_ws;
  double* parta = (double*)(ws + OFF_PARTA);
  double* colf  = (double*)(ws + OFF_COLF);
  int*    cnt   = (int*)   (ws + OFF_CNT);
  float*  psum  = (float*) (ws + OFF_PSUM);
  float*  pmass = (float*) (ws + OFF_PMASS);

  k_colstats<<<GRID_A, 256, 0, stream>>>((const float4*)embs, parta);
  k_colreduce<<<128, 256, 0, stream>>>(parta, colf);
  k_count<<<1, 64, 0, stream>>>(colf, cnt);
  k_main<<<GRID_C, 64, 0, stream>>>((const float4*)embs, (const float4*)gum, cent,
                                    cnt, psum, pmass);
  k_final<<<512, 256, 0, stream>>>(psum, pmass, cnt, (float*)d_out);
}

// Round 2
// 241.324 us; speedup vs baseline: 1.1290x; 1.1290x over previous
//
#include <hip/hip_runtime.h>
#include <math.h>

#define T_TOK   500000
#define NF4     8000000      // float4 count of token_embs
#define NTILES  7813         // ceil(500000/64)
#define GRID_A  1024
#define GRID_M  3328         // 13 1-wave blocks per CU (LDS-capped)
#define PROW    520          // per-block partial row: 512 sums + 8 masses

typedef __attribute__((ext_vector_type(8))) short bf16x8;
typedef __attribute__((ext_vector_type(4))) float f32x4;

// ws layout (bytes)
#define OFF_PARTA 0u                  // double[GRID_A][128]  (1 MB)
#define OFF_COLF  (1u<<20)            // double[128]
#define OFF_CNT   ((1u<<20) + 1024u)  // int
#define OFF_C2    ((1u<<20) + 1152u)  // float[8]
#define OFF_P     (2u<<20)            // float[GRID_M][PROW]  (~6.9 MB)

__device__ __forceinline__ unsigned cvt_pk_bf16(float lo, float hi) {
  unsigned r;
  asm("v_cvt_pk_bf16_f32 %0, %1, %2" : "=v"(r) : "v"(lo), "v"(hi));
  return r;
}

// ---------------- Pass A: per-column sum / sumsq (double) — unchanged ----------------
__global__ __launch_bounds__(256) void k_colstats(const float4* __restrict__ x4,
                                                  double* __restrict__ parta) {
  const int tid  = threadIdx.x;
  const int gtid = blockIdx.x * 256 + tid;
  double s0=0,s1=0,s2=0,s3=0,q0=0,q1=0,q2=0,q3=0;
  for (int f = gtid; f < NF4; f += GRID_A * 256) {
    float4 v = x4[f];
    double a=v.x, b=v.y, c=v.z, d=v.w;
    s0+=a; s1+=b; s2+=c; s3+=d;
    q0+=a*a; q1+=b*b; q2+=c*c; q3+=d*d;
  }
  __shared__ double red[256][4];
  red[tid][0]=s0; red[tid][1]=s1; red[tid][2]=s2; red[tid][3]=s3;
  __syncthreads();
  if (tid < 64) {
    int g = tid >> 2, i = tid & 3;
    double t = 0;
    #pragma unroll
    for (int j = 0; j < 16; j++) t += red[g + 16*j][i];
    parta[(size_t)blockIdx.x * 128 + tid] = t;
  }
  __syncthreads();
  red[tid][0]=q0; red[tid][1]=q1; red[tid][2]=q2; red[tid][3]=q3;
  __syncthreads();
  if (tid < 64) {
    int g = tid >> 2, i = tid & 3;
    double t = 0;
    #pragma unroll
    for (int j = 0; j < 16; j++) t += red[g + 16*j][i];
    parta[(size_t)blockIdx.x * 128 + 64 + tid] = t;
  }
}

// ---------------- Pass B1: reduce block partials — unchanged ----------------
__global__ __launch_bounds__(256) void k_colreduce(const double* __restrict__ parta,
                                                   double* __restrict__ colf) {
  const int c = blockIdx.x;  // 0..127
  double t = 0;
  for (int b = threadIdx.x; b < GRID_A; b += 256) t += parta[(size_t)b * 128 + c];
  __shared__ double r[256];
  r[threadIdx.x] = t;
  __syncthreads();
  for (int s = 128; s > 0; s >>= 1) {
    if (threadIdx.x < s) r[threadIdx.x] += r[threadIdx.x + s];
    __syncthreads();
  }
  if (threadIdx.x == 0) colf[c] = r[0];
}

// ---------------- Pass B2: variance -> cluster_count, plus ||c_k||^2 ----------------
__global__ __launch_bounds__(512) void k_count2(const double* __restrict__ colf,
                                                const float* __restrict__ cm,
                                                int* __restrict__ cnt,
                                                float* __restrict__ c2w) {
  const int w = threadIdx.x >> 6, d = threadIdx.x & 63;
  float v = cm[w * 64 + d];
  float s = v * v;
  for (int off = 1; off <= 32; off <<= 1) s += __shfl_xor(s, off);
  if (d == 0) c2w[w] = s;
  if (threadIdx.x < 64) {
    int c = threadIdx.x;
    double sum = colf[c], sq = colf[64 + c];
    double var = (sq - sum * sum / (double)T_TOK) / (double)(T_TOK - 1);
    for (int off = 32; off; off >>= 1) var += __shfl_xor(var, off);
    if (c == 0) {
      double vm = var / 64.0;
      int kk = (int)floor(vm * 5.0 + 2.0);
      if (kk < 2) kk = 2;
      if (kk > 8) kk = 8;
      *cnt = kk;
    }
  }
}

// ---------------- Pass C: MFMA dots + gumbel softmax + MFMA accumulation ----------------
// Layouts (16x16x32 bf16): A-frag row=lane&15, k=(lane>>4)*8+j (contig);
// B-frag col=lane&15, same k; C/D col=lane&15, row=(lane>>4)*4+reg.
__global__ __launch_bounds__(64, 4) void k_main(const float4* __restrict__ x4,
                                                const float* __restrict__ gum,
                                                const float* __restrict__ cm,
                                                const float* __restrict__ c2w,
                                                const int* __restrict__ cntp,
                                                float* __restrict__ P) {
  const int lane = threadIdx.x;
  const int li = lane & 15, lg = lane >> 4;
  __shared__ unsigned short XbfT[64 * 72];  // [dim][tok ^ swz], stride 72 ush (16B-aligned rows)
  __shared__ unsigned short Abf[16 * 72];   // [cluster(pad16)][tok]

  union FB { bf16x8 v; unsigned u[4]; };

  // hoisted centers B-frag for dots: col=li (cluster, 8..15 zero), k=h*32+lg*8+j dims
  FB cb[2];
  #pragma unroll
  for (int h = 0; h < 2; h++) {
    float4 u0 = make_float4(0.f,0.f,0.f,0.f), u1 = u0;
    if (li < 8) {
      const float4* cp = (const float4*)(cm + li * 64 + h * 32 + lg * 8);
      u0 = cp[0]; u1 = cp[1];
    }
    cb[h].u[0] = cvt_pk_bf16(u0.x, u0.y); cb[h].u[1] = cvt_pk_bf16(u0.z, u0.w);
    cb[h].u[2] = cvt_pk_bf16(u1.x, u1.y); cb[h].u[3] = cvt_pk_bf16(u1.z, u1.w);
  }
  const float c2s = (li < 8) ? c2w[li] : 0.f;
  const int cnt = *cntp;

  f32x4 acc[4] = {{0,0,0,0},{0,0,0,0},{0,0,0,0},{0,0,0,0}};
  float msr = 0.f;

  for (int tile = blockIdx.x; tile < NTILES; tile += GRID_M) {
    const int t0 = tile * 64;
    #pragma unroll
    for (int m = 0; m < 4; m++) {
      const int tok = t0 + m * 16 + li;
      const bool tv = tok < T_TOK;
      FB xa[2];
      #pragma unroll
      for (int h = 0; h < 2; h++) {
        float4 a0 = make_float4(0.f,0.f,0.f,0.f), a1 = a0;
        if (tv) {
          a0 = x4[tok * 16 + h * 8 + lg * 2];
          a1 = x4[tok * 16 + h * 8 + lg * 2 + 1];
        }
        xa[h].u[0] = cvt_pk_bf16(a0.x, a0.y); xa[h].u[1] = cvt_pk_bf16(a0.z, a0.w);
        xa[h].u[2] = cvt_pk_bf16(a1.x, a1.y); xa[h].u[3] = cvt_pk_bf16(a1.z, a1.w);
        // scatter to XbfT (token-transposed, swizzled on token bits 3-5)
        const int tl = m * 16 + li;
        #pragma unroll
        for (int j = 0; j < 8; j++) {
          int d = h * 32 + lg * 8 + j;
          int ts = tl ^ (((d >> 3) & 7) << 3);
          unsigned w = xa[h].u[j >> 1];
          XbfT[d * 72 + ts] = (unsigned short)((j & 1) ? (w >> 16) : (w & 0xffffu));
        }
      }
      // dots: C[m-tile tokens][clusters]
      f32x4 dC = {0,0,0,0};
      dC = __builtin_amdgcn_mfma_f32_16x16x32_bf16(xa[0].v, cb[0].v, dC, 0, 0, 0);
      dC = __builtin_amdgcn_mfma_f32_16x16x32_bf16(xa[1].v, cb[1].v, dC, 0, 0, 0);
      // softmax: lane holds tokens t0+m*16+lg*4+r at cluster li
      float lgt[4], a4[4];
      bool okr[4];
      #pragma unroll
      for (int r = 0; r < 4; r++) {
        int T = t0 + m * 16 + lg * 4 + r;
        int Tc = (T < T_TOK) ? T : (T_TOK - 1);
        float g = gum[Tc * 8 + (li & 7)];
        float nz = -__logf(-__logf(g));
        bool ok = (li < cnt) && (T < T_TOK);
        okr[r] = ok;
        lgt[r] = ok ? (2.f * dC[r] - c2s + nz) : -1e30f;  // x^2 cancels in softmax
      }
      float mx[4] = {lgt[0], lgt[1], lgt[2], lgt[3]};
      #pragma unroll
      for (int s = 1; s <= 4; s <<= 1) {
        #pragma unroll
        for (int r = 0; r < 4; r++) mx[r] = fmaxf(mx[r], __shfl_xor(mx[r], s));
      }
      float e[4], sm[4];
      #pragma unroll
      for (int r = 0; r < 4; r++) { e[r] = __expf(lgt[r] - mx[r]); sm[r] = e[r]; }
      #pragma unroll
      for (int s = 1; s <= 4; s <<= 1) {
        #pragma unroll
        for (int r = 0; r < 4; r++) sm[r] += __shfl_xor(sm[r], s);
      }
      #pragma unroll
      for (int r = 0; r < 4; r++) {
        float inv;
        asm("v_rcp_f32 %0, %1" : "=v"(inv) : "v"(sm[r]));
        a4[r] = okr[r] ? e[r] * inv : 0.f;
        msr += a4[r];
      }
      unsigned p0 = cvt_pk_bf16(a4[0], a4[1]), p1 = cvt_pk_bf16(a4[2], a4[3]);
      *(uint2*)&Abf[li * 72 + m * 16 + lg * 4] = make_uint2(p0, p1);
    }
    __syncthreads();  // 1-wave block: compiles to waitcnt
    // accumulation: cluster_sums += assign^T * X
    FB af[2];
    af[0].v = *(bf16x8*)&Abf[li * 72 + lg * 8];
    af[1].v = *(bf16x8*)&Abf[li * 72 + 32 + lg * 8];
    #pragma unroll
    for (int n = 0; n < 4; n++) {
      int d = n * 16 + li;
      int sw = ((d >> 3) & 7) << 3;
      #pragma unroll
      for (int kh = 0; kh < 2; kh++) {
        bf16x8 xb = *(bf16x8*)&XbfT[d * 72 + ((kh * 32 + lg * 8) ^ sw)];
        acc[n] = __builtin_amdgcn_mfma_f32_16x16x32_bf16(af[kh].v, xb, acc[n], 0, 0, 0);
      }
    }
    __syncthreads();
  }
  // per-block partials: [block][512 sums + 8 masses], contiguous
  #pragma unroll
  for (int n = 0; n < 4; n++) {
    #pragma unroll
    for (int r = 0; r < 4; r++) {
      int cl = lg * 4 + r;
      if (cl < 8) P[(size_t)blockIdx.x * PROW + cl * 64 + n * 16 + li] = acc[n][r];
    }
  }
  msr += __shfl_xor(msr, 16);
  msr += __shfl_xor(msr, 32);
  if (lane < 8) P[(size_t)blockIdx.x * PROW + 512 + lane] = msr;
}

// ---------------- Pass D: reduce partials + normalize ----------------
__global__ __launch_bounds__(256) void k_final(const float* __restrict__ P,
                                               const int* __restrict__ cntp,
                                               float* __restrict__ out) {
  const int kd = blockIdx.x;  // 0..511
  const int k = kd >> 6;
  float s = 0.f, ms = 0.f;
  #pragma unroll
  for (int i = 0; i < 13; i++) {
    int row = threadIdx.x + i * 256;  // 13*256 == GRID_M
    s  += P[(size_t)row * PROW + kd];
    ms += P[(size_t)row * PROW + 512 + k];
  }
  __shared__ float rs[256], rm[256];
  rs[threadIdx.x] = s; rm[threadIdx.x] = ms;
  __syncthreads();
  for (int t = 128; t > 0; t >>= 1) {
    if (threadIdx.x < t) { rs[threadIdx.x] += rs[threadIdx.x + t]; rm[threadIdx.x] += rm[threadIdx.x + t]; }
    __syncthreads();
  }
  if (threadIdx.x == 0) {
    int cnt = *cntp;
    out[kd] = (k < cnt) ? rs[0] / (rm[0] + 1e-8f) : 0.f;
  }
}

extern "C" void kernel_launch(void* const* d_in, const int* in_sizes, int n_in,
                              void* d_out, int out_size, void* d_ws, size_t ws_size,
                              hipStream_t stream) {
  const float* embs = (const float*)d_in[0];
  const float* gum  = (const float*)d_in[1];
  const float* cent = (const float*)d_in[2];
  char* ws = (char*)d_ws;
  double* parta = (double*)(ws + OFF_PARTA);
  double* colf  = (double*)(ws + OFF_COLF);
  int*    cnt   = (int*)   (ws + OFF_CNT);
  float*  c2w   = (float*) (ws + OFF_C2);
  float*  P     = (float*) (ws + OFF_P);

  k_colstats<<<GRID_A, 256, 0, stream>>>((const float4*)embs, parta);
  k_colreduce<<<128, 256, 0, stream>>>(parta, colf);
  k_count2<<<1, 512, 0, stream>>>(colf, cent, cnt, c2w);
  k_main<<<GRID_M, 64, 0, stream>>>((const float4*)embs, gum, cent, c2w, cnt, P);
  k_final<<<512, 256, 0, stream>>>(P, cnt, (float*)d_out);
}

// Round 3
// 236.561 us; speedup vs baseline: 1.1517x; 1.0201x over previous
//
#include <hip/hip_runtime.h>
#include <math.h>

#define T_TOK   500000
#define NF4     8000000      // float4 count of token_embs
#define NTILES  7813         // ceil(500000/64)
#define GRID_A  1024
#define GRID_M  3328         // 13*256 1-wave blocks
#define PROW    520          // per-block partial row: 512 sums + 8 masses

typedef __attribute__((ext_vector_type(8))) short bf16x8;
typedef __attribute__((ext_vector_type(4))) float f32x4;

union FB { bf16x8 v; unsigned u[4]; };

// ws layout (bytes)
#define OFF_PARTA 0u                  // double[GRID_A][128]  (1 MB)
#define OFF_COLF  (1u<<20)            // double[128]
#define OFF_CNT   ((1u<<20) + 1024u)  // int
#define OFF_C2    ((1u<<20) + 1152u)  // float[8]
#define OFF_P     (2u<<20)            // float[GRID_M][PROW]  (~6.9 MB)

__device__ __forceinline__ unsigned cvt_pk_bf16(float lo, float hi) {
  unsigned r;
  asm("v_cvt_pk_bf16_f32 %0, %1, %2" : "=v"(r) : "v"(lo), "v"(hi));
  return r;
}

// ---------------- Pass A: per-column sum / sumsq (double) — unchanged ----------------
__global__ __launch_bounds__(256) void k_colstats(const float4* __restrict__ x4,
                                                  double* __restrict__ parta) {
  const int tid  = threadIdx.x;
  const int gtid = blockIdx.x * 256 + tid;
  double s0=0,s1=0,s2=0,s3=0,q0=0,q1=0,q2=0,q3=0;
  for (int f = gtid; f < NF4; f += GRID_A * 256) {
    float4 v = x4[f];
    double a=v.x, b=v.y, c=v.z, d=v.w;
    s0+=a; s1+=b; s2+=c; s3+=d;
    q0+=a*a; q1+=b*b; q2+=c*c; q3+=d*d;
  }
  __shared__ double red[256][4];
  red[tid][0]=s0; red[tid][1]=s1; red[tid][2]=s2; red[tid][3]=s3;
  __syncthreads();
  if (tid < 64) {
    int g = tid >> 2, i = tid & 3;
    double t = 0;
    #pragma unroll
    for (int j = 0; j < 16; j++) t += red[g + 16*j][i];
    parta[(size_t)blockIdx.x * 128 + tid] = t;
  }
  __syncthreads();
  red[tid][0]=q0; red[tid][1]=q1; red[tid][2]=q2; red[tid][3]=q3;
  __syncthreads();
  if (tid < 64) {
    int g = tid >> 2, i = tid & 3;
    double t = 0;
    #pragma unroll
    for (int j = 0; j < 16; j++) t += red[g + 16*j][i];
    parta[(size_t)blockIdx.x * 128 + 64 + tid] = t;
  }
}

// ---------------- Pass B1: reduce block partials — unchanged ----------------
__global__ __launch_bounds__(256) void k_colreduce(const double* __restrict__ parta,
                                                   double* __restrict__ colf) {
  const int c = blockIdx.x;  // 0..127
  double t = 0;
  for (int b = threadIdx.x; b < GRID_A; b += 256) t += parta[(size_t)b * 128 + c];
  __shared__ double r[256];
  r[threadIdx.x] = t;
  __syncthreads();
  for (int s = 128; s > 0; s >>= 1) {
    if (threadIdx.x < s) r[threadIdx.x] += r[threadIdx.x + s];
    __syncthreads();
  }
  if (threadIdx.x == 0) colf[c] = r[0];
}

// ---------------- Pass B2: variance -> cluster_count, plus ||c_k||^2 ----------------
__global__ __launch_bounds__(512) void k_count2(const double* __restrict__ colf,
                                                const float* __restrict__ cm,
                                                int* __restrict__ cnt,
                                                float* __restrict__ c2w) {
  const int w = threadIdx.x >> 6, d = threadIdx.x & 63;
  float v = cm[w * 64 + d];
  float s = v * v;
  for (int off = 1; off <= 32; off <<= 1) s += __shfl_xor(s, off);
  if (d == 0) c2w[w] = s;
  if (threadIdx.x < 64) {
    int c = threadIdx.x;
    double sum = colf[c], sq = colf[64 + c];
    double var = (sq - sum * sum / (double)T_TOK) / (double)(T_TOK - 1);
    for (int off = 32; off; off >>= 1) var += __shfl_xor(var, off);
    if (c == 0) {
      double vm = var / 64.0;
      int kk = (int)floor(vm * 5.0 + 2.0);
      if (kk < 2) kk = 2;
      if (kk > 8) kk = 8;
      *cnt = kk;
    }
  }
}

// ---------------- Pass C helpers ----------------
__device__ __forceinline__ void issue_q(const float4* __restrict__ x4, int t0m,
                                        int li, int lg,
                                        float4& r0, float4& r1, float4& r2, float4& r3) {
  const int tok = t0m + li;
  if (tok < T_TOK) {
    const float4* p = x4 + (size_t)tok * 16 + lg * 2;
    r0 = p[0]; r1 = p[1]; r2 = p[8]; r3 = p[9];
  } else {
    r0 = r1 = r2 = r3 = make_float4(0.f, 0.f, 0.f, 0.f);
  }
}

template<int MM>
__device__ __forceinline__ void process_q(
    const float4& r0, const float4& r1, const float4& r2, const float4& r3,
    const float (&gg)[4][4], int li, int lg, int t0, int cnt, float c2s,
    const FB* cb, unsigned short* XbfT, unsigned short* Abf, float& msr) {
  FB xa0, xa1;
  xa0.u[0] = cvt_pk_bf16(r0.x, r0.y); xa0.u[1] = cvt_pk_bf16(r0.z, r0.w);
  xa0.u[2] = cvt_pk_bf16(r1.x, r1.y); xa0.u[3] = cvt_pk_bf16(r1.z, r1.w);
  xa1.u[0] = cvt_pk_bf16(r2.x, r2.y); xa1.u[1] = cvt_pk_bf16(r2.z, r2.w);
  xa1.u[2] = cvt_pk_bf16(r3.x, r3.y); xa1.u[3] = cvt_pk_bf16(r3.z, r3.w);
  // scatter to XbfT (token-transposed, swizzle on token bits 3-5; d>>3 const per h)
  const int tl = MM * 16 + li;
  const int ts0 = tl ^ ((lg & 7) << 3);          // h=0: d>>3 = lg
  const int ts1 = tl ^ (((lg + 4) & 7) << 3);    // h=1: d>>3 = 4+lg
  #pragma unroll
  for (int j = 0; j < 8; j++) {
    unsigned w0 = xa0.u[j >> 1], w1 = xa1.u[j >> 1];
    XbfT[(lg * 8 + j) * 72 + ts0]      = (unsigned short)((j & 1) ? (w0 >> 16) : (w0 & 0xffffu));
    XbfT[(32 + lg * 8 + j) * 72 + ts1] = (unsigned short)((j & 1) ? (w1 >> 16) : (w1 & 0xffffu));
  }
  // dots
  f32x4 dC = {0, 0, 0, 0};
  dC = __builtin_amdgcn_mfma_f32_16x16x32_bf16(xa0.v, cb[0].v, dC, 0, 0, 0);
  dC = __builtin_amdgcn_mfma_f32_16x16x32_bf16(xa1.v, cb[1].v, dC, 0, 0, 0);
  // softmax: lane holds tokens t0+MM*16+lg*4+r at cluster li
  float lgt[4], a4[4];
  bool okr[4];
  #pragma unroll
  for (int r = 0; r < 4; r++) {
    int T = t0 + MM * 16 + lg * 4 + r;
    float nz = -__logf(-__logf(gg[MM][r]));
    bool ok = (li < cnt) && (T < T_TOK);
    okr[r] = ok;
    lgt[r] = ok ? (2.f * dC[r] - c2s + nz) : -1e30f;  // x^2 cancels in softmax
  }
  float mx[4] = {lgt[0], lgt[1], lgt[2], lgt[3]};
  #pragma unroll
  for (int s = 1; s <= 4; s <<= 1) {
    #pragma unroll
    for (int r = 0; r < 4; r++) mx[r] = fmaxf(mx[r], __shfl_xor(mx[r], s));
  }
  float e[4], sm[4];
  #pragma unroll
  for (int r = 0; r < 4; r++) { e[r] = __expf(lgt[r] - mx[r]); sm[r] = e[r]; }
  #pragma unroll
  for (int s = 1; s <= 4; s <<= 1) {
    #pragma unroll
    for (int r = 0; r < 4; r++) sm[r] += __shfl_xor(sm[r], s);
  }
  #pragma unroll
  for (int r = 0; r < 4; r++) {
    float inv;
    asm("v_rcp_f32 %0, %1" : "=v"(inv) : "v"(sm[r]));
    a4[r] = okr[r] ? e[r] * inv : 0.f;
    msr += a4[r];
  }
  unsigned p0 = cvt_pk_bf16(a4[0], a4[1]), p1 = cvt_pk_bf16(a4[2], a4[3]);
  *(uint2*)&Abf[li * 72 + MM * 16 + lg * 4] = make_uint2(p0, p1);
}

// ---------------- Pass C: MFMA dots + gumbel softmax + MFMA accumulation ----------------
__global__ __launch_bounds__(64) void k_main(const float4* __restrict__ x4,
                                             const float* __restrict__ gum,
                                             const float* __restrict__ cm,
                                             const float* __restrict__ c2w,
                                             const int* __restrict__ cntp,
                                             float* __restrict__ P) {
  const int lane = threadIdx.x & 63;
  const int li = lane & 15, lg = lane >> 4;
  __shared__ unsigned short LDSH[5760];  // XbfT[64][72] @0 ; Abf[16][72] @4608
  unsigned short* XbfT = LDSH;
  unsigned short* Abf  = LDSH + 4608;

  // hoisted centers B-frag for dots: col=li (cluster, 8..15 zero), k=h*32+lg*8+j dims
  FB cb[2];
  #pragma unroll
  for (int h = 0; h < 2; h++) {
    float4 u0 = make_float4(0.f, 0.f, 0.f, 0.f), u1 = u0;
    if (li < 8) {
      const float4* cp = (const float4*)(cm + li * 64 + h * 32 + lg * 8);
      u0 = cp[0]; u1 = cp[1];
    }
    cb[h].u[0] = cvt_pk_bf16(u0.x, u0.y); cb[h].u[1] = cvt_pk_bf16(u0.z, u0.w);
    cb[h].u[2] = cvt_pk_bf16(u1.x, u1.y); cb[h].u[3] = cvt_pk_bf16(u1.z, u1.w);
  }
  const float c2s = (li < 8) ? c2w[li] : 0.f;
  const int cnt = *cntp;

  f32x4 acc[4] = {{0,0,0,0},{0,0,0,0},{0,0,0,0},{0,0,0,0}};
  float msr = 0.f;

  float4 a0, a1, a2, a3, b0, b1, b2, b3;
  int tile = blockIdx.x;
  if (tile < NTILES) issue_q(x4, tile * 64, li, lg, a0, a1, a2, a3);

  for (; tile < NTILES; tile += GRID_M) {
    const int t0 = tile * 64;
    // gumbel prefetch for the whole tile (16 b32, coalesced 512B segments)
    float gg[4][4];
    #pragma unroll
    for (int m = 0; m < 4; m++) {
      #pragma unroll
      for (int r = 0; r < 4; r++) {
        int T = t0 + m * 16 + lg * 4 + r;
        int Tc = (T < T_TOK) ? T : (T_TOK - 1);
        gg[m][r] = gum[(size_t)Tc * 8 + (li & 7)];
      }
    }
    // depth-1 quarter-tile pipeline, cross-tile on the last quarter
    issue_q(x4, t0 + 16, li, lg, b0, b1, b2, b3);
    process_q<0>(a0, a1, a2, a3, gg, li, lg, t0, cnt, c2s, cb, XbfT, Abf, msr);
    issue_q(x4, t0 + 32, li, lg, a0, a1, a2, a3);
    process_q<1>(b0, b1, b2, b3, gg, li, lg, t0, cnt, c2s, cb, XbfT, Abf, msr);
    issue_q(x4, t0 + 48, li, lg, b0, b1, b2, b3);
    process_q<2>(a0, a1, a2, a3, gg, li, lg, t0, cnt, c2s, cb, XbfT, Abf, msr);
    if (tile + GRID_M < NTILES)
      issue_q(x4, (tile + GRID_M) * 64, li, lg, a0, a1, a2, a3);
    process_q<3>(b0, b1, b2, b3, gg, li, lg, t0, cnt, c2s, cb, XbfT, Abf, msr);

    // wave-local LDS fence (1-wave block): scatter/Abf writes -> acc reads.
    // Deliberately NOT __syncthreads(): keeps prefetched global loads in flight.
    asm volatile("s_waitcnt lgkmcnt(0)" ::: "memory");

    // accumulation: cluster_sums += assign^T * X
    FB af0, af1;
    af0.v = *(bf16x8*)&Abf[li * 72 + lg * 8];
    af1.v = *(bf16x8*)&Abf[li * 72 + 32 + lg * 8];
    #pragma unroll
    for (int n = 0; n < 4; n++) {
      const int d = n * 16 + li;
      const int sw = ((d >> 3) & 7) << 3;
      bf16x8 xb0 = *(bf16x8*)&XbfT[d * 72 + ((lg * 8) ^ sw)];
      acc[n] = __builtin_amdgcn_mfma_f32_16x16x32_bf16(af0.v, xb0, acc[n], 0, 0, 0);
      bf16x8 xb1 = *(bf16x8*)&XbfT[d * 72 + ((32 + lg * 8) ^ sw)];
      acc[n] = __builtin_amdgcn_mfma_f32_16x16x32_bf16(af1.v, xb1, acc[n], 0, 0, 0);
    }
    // acc reads done before next tile's scatter (in-order DS + clobber ordering)
    asm volatile("s_waitcnt lgkmcnt(0)" ::: "memory");
  }

  // per-block partials: [block][512 sums + 8 masses], contiguous
  #pragma unroll
  for (int n = 0; n < 4; n++) {
    #pragma unroll
    for (int r = 0; r < 4; r++) {
      int cl = lg * 4 + r;
      if (cl < 8) P[(size_t)blockIdx.x * PROW + cl * 64 + n * 16 + li] = acc[n][r];
    }
  }
  msr += __shfl_xor(msr, 16);
  msr += __shfl_xor(msr, 32);
  if (lane < 8) P[(size_t)blockIdx.x * PROW + 512 + lane] = msr;
}

// ---------------- Pass D: reduce partials + normalize ----------------
__global__ __launch_bounds__(256) void k_final(const float* __restrict__ P,
                                               const int* __restrict__ cntp,
                                               float* __restrict__ out) {
  const int kd = blockIdx.x;  // 0..511
  const int k = kd >> 6;
  float s = 0.f, ms = 0.f;
  #pragma unroll
  for (int i = 0; i < 13; i++) {
    int row = threadIdx.x + i * 256;  // 13*256 == GRID_M
    s  += P[(size_t)row * PROW + kd];
    ms += P[(size_t)row * PROW + 512 + k];
  }
  __shared__ float rs[256], rm[256];
  rs[threadIdx.x] = s; rm[threadIdx.x] = ms;
  __syncthreads();
  for (int t = 128; t > 0; t >>= 1) {
    if (threadIdx.x < t) { rs[threadIdx.x] += rs[threadIdx.x + t]; rm[threadIdx.x] += rm[threadIdx.x + t]; }
    __syncthreads();
  }
  if (threadIdx.x == 0) {
    int cnt = *cntp;
    out[kd] = (k < cnt) ? rs[0] / (rm[0] + 1e-8f) : 0.f;
  }
}

extern "C" void kernel_launch(void* const* d_in, const int* in_sizes, int n_in,
                              void* d_out, int out_size, void* d_ws, size_t ws_size,
                              hipStream_t stream) {
  const float* embs = (const float*)d_in[0];
  const float* gum  = (const float*)d_in[1];
  const float* cent = (const float*)d_in[2];
  char* ws = (char*)d_ws;
  double* parta = (double*)(ws + OFF_PARTA);
  double* colf  = (double*)(ws + OFF_COLF);
  int*    cnt   = (int*)   (ws + OFF_CNT);
  float*  c2w   = (float*) (ws + OFF_C2);
  float*  P     = (float*) (ws + OFF_P);

  k_colstats<<<GRID_A, 256, 0, stream>>>((const float4*)embs, parta);
  k_colreduce<<<128, 256, 0, stream>>>(parta, colf);
  k_count2<<<1, 512, 0, stream>>>(colf, cent, cnt, c2w);
  k_main<<<GRID_M, 64, 0, stream>>>((const float4*)embs, gum, cent, c2w, cnt, P);
  k_final<<<512, 256, 0, stream>>>(P, cnt, (float*)d_out);
}

// Round 6
// 229.934 us; speedup vs baseline: 1.1849x; 1.0288x over previous
//
#include <hip/hip_runtime.h>
#include <math.h>

#define T_TOK   500000
#define NF4     8000000      // float4 count of token_embs
#define NTILES  7813         // ceil(500000/64)
#define GRID_A  1024
#define GRID_M  4096         // 16 1-wave blocks per CU (LDS arena 10240 B)
#define PROW    520          // per-stream partial row: 512 sums + 8 masses

typedef __attribute__((ext_vector_type(8))) short bf16x8;
typedef __attribute__((ext_vector_type(4))) float f32x4;

union FB { bf16x8 v; unsigned u[4]; };

// ws layout (bytes)
#define OFF_PARTA 0u                  // double[GRID_A][128]  (1 MB)
#define OFF_COLF  (1u<<20)            // double[128]
#define OFF_CNT   ((1u<<20) + 1024u)  // int
#define OFF_C2    ((1u<<20) + 1152u)  // float[8]
#define OFF_P     (2u<<20)            // float[GRID_M][PROW]  (~8.5 MB)
#define OFF_P2    (12u<<20)           // float[256][PROW]     (~0.53 MB)

__device__ __forceinline__ unsigned cvt_pk_bf16(float lo, float hi) {
  unsigned r;
  asm("v_cvt_pk_bf16_f32 %0, %1, %2" : "=v"(r) : "v"(lo), "v"(hi));
  return r;
}

// ---------------- Pass A: per-column sum / sumsq (double) — unchanged ----------------
__global__ __launch_bounds__(256) void k_colstats(const float4* __restrict__ x4,
                                                  double* __restrict__ parta) {
  const int tid  = threadIdx.x;
  const int gtid = blockIdx.x * 256 + tid;
  double s0=0,s1=0,s2=0,s3=0,q0=0,q1=0,q2=0,q3=0;
  for (int f = gtid; f < NF4; f += GRID_A * 256) {
    float4 v = x4[f];
    double a=v.x, b=v.y, c=v.z, d=v.w;
    s0+=a; s1+=b; s2+=c; s3+=d;
    q0+=a*a; q1+=b*b; q2+=c*c; q3+=d*d;
  }
  __shared__ double red[256][4];
  red[tid][0]=s0; red[tid][1]=s1; red[tid][2]=s2; red[tid][3]=s3;
  __syncthreads();
  if (tid < 64) {
    int g = tid >> 2, i = tid & 3;
    double t = 0;
    #pragma unroll
    for (int j = 0; j < 16; j++) t += red[g + 16*j][i];
    parta[(size_t)blockIdx.x * 128 + tid] = t;
  }
  __syncthreads();
  red[tid][0]=q0; red[tid][1]=q1; red[tid][2]=q2; red[tid][3]=q3;
  __syncthreads();
  if (tid < 64) {
    int g = tid >> 2, i = tid & 3;
    double t = 0;
    #pragma unroll
    for (int j = 0; j < 16; j++) t += red[g + 16*j][i];
    parta[(size_t)blockIdx.x * 128 + 64 + tid] = t;
  }
}

// ---------------- Pass B1: reduce block partials — unchanged ----------------
__global__ __launch_bounds__(256) void k_colreduce(const double* __restrict__ parta,
                                                   double* __restrict__ colf) {
  const int c = blockIdx.x;  // 0..127
  double t = 0;
  for (int b = threadIdx.x; b < GRID_A; b += 256) t += parta[(size_t)b * 128 + c];
  __shared__ double r[256];
  r[threadIdx.x] = t;
  __syncthreads();
  for (int s = 128; s > 0; s >>= 1) {
    if (threadIdx.x < s) r[threadIdx.x] += r[threadIdx.x + s];
    __syncthreads();
  }
  if (threadIdx.x == 0) colf[c] = r[0];
}

// ---------------- Pass B2: variance -> cluster_count, plus ||c_k||^2 ----------------
__global__ __launch_bounds__(512) void k_count2(const double* __restrict__ colf,
                                                const float* __restrict__ cm,
                                                int* __restrict__ cnt,
                                                float* __restrict__ c2w) {
  const int w = threadIdx.x >> 6, d = threadIdx.x & 63;
  float v = cm[w * 64 + d];
  float s = v * v;
  for (int off = 1; off <= 32; off <<= 1) s += __shfl_xor(s, off);
  if (d == 0) c2w[w] = s;
  if (threadIdx.x < 64) {
    int c = threadIdx.x;
    double sum = colf[c], sq = colf[64 + c];
    double var = (sq - sum * sum / (double)T_TOK) / (double)(T_TOK - 1);
    for (int off = 32; off; off >>= 1) var += __shfl_xor(var, off);
    if (c == 0) {
      double vm = var / 64.0;
      int kk = (int)floor(vm * 5.0 + 2.0);
      if (kk < 2) kk = 2;
      if (kk > 8) kk = 8;
      *cnt = kk;
    }
  }
}

// ---------------- Pass C helpers ----------------
// LDS swizzle: element (d,t) of XbfT at  d*64 + B8(d,t)*8 + (t&7),
// B8 = ((t>>3)+(d&7)+(d>>3)) & 7.  Keeps 8-token blocks contiguous (b128 reads),
// distinct bank-quads within each 8-lane phase. Same scheme for Abf (d->cluster).
__device__ __forceinline__ void issue_q(const float4* __restrict__ x4, int t0m,
                                        int li, int lg,
                                        float4& r0, float4& r1, float4& r2, float4& r3) {
  const int tok = t0m + li;
  if (tok < T_TOK) {
    const float4* p = x4 + (size_t)tok * 16 + lg * 2;
    r0 = p[0]; r1 = p[1]; r2 = p[8]; r3 = p[9];
  } else {
    r0 = r1 = r2 = r3 = make_float4(0.f, 0.f, 0.f, 0.f);
  }
}

template<int MM>
__device__ __forceinline__ void process_q(
    const float4& r0, const float4& r1, const float4& r2, const float4& r3,
    const float (&gg)[4][4], int li, int lg, int t0, int cnt, float c2s,
    const FB* cb, unsigned short* XbfT, unsigned short* Abf, float& msr) {
  FB xa0, xa1;
  xa0.u[0] = cvt_pk_bf16(r0.x, r0.y); xa0.u[1] = cvt_pk_bf16(r0.z, r0.w);
  xa0.u[2] = cvt_pk_bf16(r1.x, r1.y); xa0.u[3] = cvt_pk_bf16(r1.z, r1.w);
  xa1.u[0] = cvt_pk_bf16(r2.x, r2.y); xa1.u[1] = cvt_pk_bf16(r2.z, r2.w);
  xa1.u[2] = cvt_pk_bf16(r3.x, r3.y); xa1.u[3] = cvt_pk_bf16(r3.z, r3.w);
  // scatter to XbfT: token t = MM*16+li, dims d = lg*8+j (h0), 32+lg*8+j (h1)
  const int tlow  = li & 7;
  const int thigh = MM * 2 + (li >> 3);
  #pragma unroll
  for (int j = 0; j < 8; j++) {
    unsigned w0 = xa0.u[j >> 1], w1 = xa1.u[j >> 1];
    unsigned short h0 = (unsigned short)((j & 1) ? (w0 >> 16) : (w0 & 0xffffu));
    unsigned short h1 = (unsigned short)((j & 1) ? (w1 >> 16) : (w1 & 0xffffu));
    int a0 = (lg * 8 + j) * 64      + (((thigh + j + lg) & 7) << 3)     + tlow;
    int a1 = (32 + lg * 8 + j) * 64 + (((thigh + j + 4 + lg) & 7) << 3) + tlow;
    XbfT[a0] = h0;
    XbfT[a1] = h1;
  }
  // dots
  f32x4 dC = {0, 0, 0, 0};
  dC = __builtin_amdgcn_mfma_f32_16x16x32_bf16(xa0.v, cb[0].v, dC, 0, 0, 0);
  dC = __builtin_amdgcn_mfma_f32_16x16x32_bf16(xa1.v, cb[1].v, dC, 0, 0, 0);
  // softmax: lane holds tokens t0+MM*16+lg*4+r at cluster li
  float lgt[4], a4[4];
  bool okr[4];
  #pragma unroll
  for (int r = 0; r < 4; r++) {
    int T = t0 + MM * 16 + lg * 4 + r;
    float nz = -__logf(-__logf(gg[MM][r]));
    bool ok = (li < cnt) && (T < T_TOK);
    okr[r] = ok;
    lgt[r] = ok ? (2.f * dC[r] - c2s + nz) : -1e30f;  // x^2 cancels in softmax
  }
  float mx[4] = {lgt[0], lgt[1], lgt[2], lgt[3]};
  #pragma unroll
  for (int s = 1; s <= 4; s <<= 1) {
    #pragma unroll
    for (int r = 0; r < 4; r++) mx[r] = fmaxf(mx[r], __shfl_xor(mx[r], s));
  }
  float e[4], sm[4];
  #pragma unroll
  for (int r = 0; r < 4; r++) { e[r] = __expf(lgt[r] - mx[r]); sm[r] = e[r]; }
  #pragma unroll
  for (int s = 1; s <= 4; s <<= 1) {
    #pragma unroll
    for (int r = 0; r < 4; r++) sm[r] += __shfl_xor(sm[r], s);
  }
  #pragma unroll
  for (int r = 0; r < 4; r++) {
    float inv;
    asm("v_rcp_f32 %0, %1" : "=v"(inv) : "v"(sm[r]));
    a4[r] = okr[r] ? e[r] * inv : 0.f;
    msr += a4[r];
  }
  // Abf element (cluster=li, token=MM*16+lg*4+r): 4 contiguous ush within an 8-block
  unsigned p0 = cvt_pk_bf16(a4[0], a4[1]), p1 = cvt_pk_bf16(a4[2], a4[3]);
  int aa = li * 64 + (((MM * 2 + (lg >> 1) + (li & 7) + (li >> 3)) & 7) << 3) + ((lg & 1) << 2);
  *(uint2*)&Abf[aa] = make_uint2(p0, p1);
}

// ---------------- Pass C: MFMA dots + gumbel softmax + MFMA accumulation ----------------
__global__ __launch_bounds__(64) void k_main(const float4* __restrict__ x4,
                                             const float* __restrict__ gum,
                                             const float* __restrict__ cm,
                                             const float* __restrict__ c2w,
                                             const int* __restrict__ cntp,
                                             float* __restrict__ P) {
  const int lane = threadIdx.x & 63;
  const int li = lane & 15, lg = lane >> 4;
  __shared__ unsigned short LDSH[5120];  // XbfT[4096] @0 ; Abf[1024] @4096 -> 10240 B
  unsigned short* XbfT = LDSH;
  unsigned short* Abf  = LDSH + 4096;

  // hoisted centers B-frag for dots: col=li (cluster, 8..15 zero), k=h*32+lg*8+j dims
  FB cb[2];
  #pragma unroll
  for (int h = 0; h < 2; h++) {
    float4 u0 = make_float4(0.f, 0.f, 0.f, 0.f), u1 = u0;
    if (li < 8) {
      const float4* cp = (const float4*)(cm + li * 64 + h * 32 + lg * 8);
      u0 = cp[0]; u1 = cp[1];
    }
    cb[h].u[0] = cvt_pk_bf16(u0.x, u0.y); cb[h].u[1] = cvt_pk_bf16(u0.z, u0.w);
    cb[h].u[2] = cvt_pk_bf16(u1.x, u1.y); cb[h].u[3] = cvt_pk_bf16(u1.z, u1.w);
  }
  const float c2s = (li < 8) ? c2w[li] : 0.f;
  const int cnt = *cntp;

  f32x4 acc[4] = {{0,0,0,0},{0,0,0,0},{0,0,0,0},{0,0,0,0}};
  float msr = 0.f;

  float4 a0, a1, a2, a3, b0, b1, b2, b3;
  int tile = blockIdx.x;
  if (tile < NTILES) issue_q(x4, tile * 64, li, lg, a0, a1, a2, a3);

  for (; tile < NTILES; tile += GRID_M) {
    const int t0 = tile * 64;
    // gumbel prefetch for the whole tile
    float gg[4][4];
    #pragma unroll
    for (int m = 0; m < 4; m++) {
      #pragma unroll
      for (int r = 0; r < 4; r++) {
        int T = t0 + m * 16 + lg * 4 + r;
        int Tc = (T < T_TOK) ? T : (T_TOK - 1);
        gg[m][r] = gum[(size_t)Tc * 8 + (li & 7)];
      }
    }
    // depth-1 quarter-tile pipeline, cross-tile on the last quarter
    issue_q(x4, t0 + 16, li, lg, b0, b1, b2, b3);
    process_q<0>(a0, a1, a2, a3, gg, li, lg, t0, cnt, c2s, cb, XbfT, Abf, msr);
    issue_q(x4, t0 + 32, li, lg, a0, a1, a2, a3);
    process_q<1>(b0, b1, b2, b3, gg, li, lg, t0, cnt, c2s, cb, XbfT, Abf, msr);
    issue_q(x4, t0 + 48, li, lg, b0, b1, b2, b3);
    process_q<2>(a0, a1, a2, a3, gg, li, lg, t0, cnt, c2s, cb, XbfT, Abf, msr);
    if (tile + GRID_M < NTILES)
      issue_q(x4, (tile + GRID_M) * 64, li, lg, a0, a1, a2, a3);
    process_q<3>(b0, b1, b2, b3, gg, li, lg, t0, cnt, c2s, cb, XbfT, Abf, msr);

    // wave-local LDS fence (1-wave block): scatter/Abf writes -> acc reads.
    asm volatile("s_waitcnt lgkmcnt(0)" ::: "memory");

    // accumulation: cluster_sums += assign^T * X
    FB af0, af1;
    const int abase = li * 64;
    const int asw   = (li & 7) + (li >> 3);
    af0.v = *(bf16x8*)&Abf[abase + (((lg + asw) & 7) << 3)];
    af1.v = *(bf16x8*)&Abf[abase + (((4 + lg + asw) & 7) << 3)];
    #pragma unroll
    for (int n = 0; n < 4; n++) {
      const int d  = n * 16 + li;
      const int dl = (li & 7) + 2 * n + (li >> 3);
      bf16x8 xb0 = *(bf16x8*)&XbfT[d * 64 + (((lg + dl) & 7) << 3)];
      acc[n] = __builtin_amdgcn_mfma_f32_16x16x32_bf16(af0.v, xb0, acc[n], 0, 0, 0);
      bf16x8 xb1 = *(bf16x8*)&XbfT[d * 64 + (((4 + lg + dl) & 7) << 3)];
      acc[n] = __builtin_amdgcn_mfma_f32_16x16x32_bf16(af1.v, xb1, acc[n], 0, 0, 0);
    }
    // acc reads done before next tile's scatter
    asm volatile("s_waitcnt lgkmcnt(0)" ::: "memory");
  }

  // per-stream partials: [block][512 sums + 8 masses], contiguous
  #pragma unroll
  for (int n = 0; n < 4; n++) {
    #pragma unroll
    for (int r = 0; r < 4; r++) {
      int cl = lg * 4 + r;
      if (cl < 8) P[(size_t)blockIdx.x * PROW + cl * 64 + n * 16 + li] = acc[n][r];
    }
  }
  msr += __shfl_xor(msr, 16);
  msr += __shfl_xor(msr, 32);
  if (lane < 8) P[(size_t)blockIdx.x * PROW + 512 + lane] = msr;
}

// ---------------- Pass D1: coalesced partial reduction 4096 -> 256 rows ----------------
__global__ __launch_bounds__(256) void k_red1(const float* __restrict__ P,
                                              float* __restrict__ P2) {
  const int b = blockIdx.x;  // 0..255, rows b*16 .. b*16+15
  for (int c = threadIdx.x; c < PROW; c += 256) {
    float s = 0.f;
    #pragma unroll
    for (int i = 0; i < 16; i++) s += P[(size_t)(b * 16 + i) * PROW + c];
    P2[(size_t)b * PROW + c] = s;
  }
}

// ---------------- Pass D2: final reduce + normalize (1-wave blocks) ----------------
__global__ __launch_bounds__(64) void k_red2(const float* __restrict__ P2,
                                             const int* __restrict__ cntp,
                                             float* __restrict__ out) {
  const int kd = blockIdx.x;  // 0..511
  const int k = kd >> 6;
  const int t = threadIdx.x;
  float s = 0.f, m = 0.f;
  #pragma unroll
  for (int i = 0; i < 4; i++) {
    int r = t + i * 64;
    s += P2[(size_t)r * PROW + kd];
    m += P2[(size_t)r * PROW + 512 + k];
  }
  for (int off = 1; off <= 32; off <<= 1) {
    s += __shfl_xor(s, off);
    m += __shfl_xor(m, off);
  }
  if (t == 0) {
    int cnt = *cntp;
    out[kd] = (k < cnt) ? s / (m + 1e-8f) : 0.f;
  }
}

extern "C" void kernel_launch(void* const* d_in, const int* in_sizes, int n_in,
                              void* d_out, int out_size, void* d_ws, size_t ws_size,
                              hipStream_t stream) {
  const float* embs = (const float*)d_in[0];
  const float* gum  = (const float*)d_in[1];
  const float* cent = (const float*)d_in[2];
  char* ws = (char*)d_ws;
  double* parta = (double*)(ws + OFF_PARTA);
  double* colf  = (double*)(ws + OFF_COLF);
  int*    cnt   = (int*)   (ws + OFF_CNT);
  float*  c2w   = (float*) (ws + OFF_C2);
  float*  P     = (float*) (ws + OFF_P);
  float*  P2    = (float*) (ws + OFF_P2);

  k_colstats<<<GRID_A, 256, 0, stream>>>((const float4*)embs, parta);
  k_colreduce<<<128, 256, 0, stream>>>(parta, colf);
  k_count2<<<1, 512, 0, stream>>>(colf, cent, cnt, c2w);
  k_main<<<GRID_M, 64, 0, stream>>>((const float4*)embs, gum, cent, c2w, cnt, P);
  k_red1<<<256, 256, 0, stream>>>(P, P2);
  k_red2<<<512, 64, 0, stream>>>(P2, cnt, (float*)d_out);
}